// Round 5
// baseline (1032.815 us; speedup 1.0000x reference)
//
#include <hip/hip_runtime.h>

// LightGCN on MI355X: 3x SpMM (COO -> CSR built in-launch) + running sum.
// N_NODES=150000, DIM=64, NNZ=4M. Dense state (38.4MB) is L3-resident.
// Strategy: CSR by row (no fp32 atomics), one wave64 per row, lane=dim.
// ws_size guard: if workspace is smaller than required (~110.4MB), launch
// nothing -> clean absmax failure (diagnostic) instead of OOB crash.

#define NUSERS 100000
#define NITEMS 50000
#define NNODES 150000
#define DIM    64
#define NNZ_E  4000000

// ---- CSR build ----------------------------------------------------------

__global__ void hist_k(const int* __restrict__ rows, int* __restrict__ deg) {
    int i = blockIdx.x * 256 + threadIdx.x;
    if (i < NNZ_E) atomicAdd(&deg[rows[i]], 1);
}

// per-256-block exclusive scan of deg -> rs (without block offsets), block totals -> bsum
__global__ void scan_block_k(const int* __restrict__ deg, int* __restrict__ rs,
                             int* __restrict__ bsum) {
    __shared__ int s[256];
    int t = threadIdx.x;
    int i = blockIdx.x * 256 + t;
    int v = (i < NNODES) ? deg[i] : 0;
    s[t] = v;
    __syncthreads();
    for (int off = 1; off < 256; off <<= 1) {
        int add = (t >= off) ? s[t - off] : 0;
        __syncthreads();
        s[t] += add;
        __syncthreads();
    }
    if (i < NNODES) rs[i] = s[t] - v;          // exclusive within block
    if (t == 255) bsum[blockIdx.x] = s[255];   // block total
}

// exclusive scan of block totals in-place (nb <= 1024)
__global__ void scan_bsum_k(int* __restrict__ bsum, int nb) {
    __shared__ int s[1024];
    int t = threadIdx.x;
    int v = (t < nb) ? bsum[t] : 0;
    s[t] = v;
    __syncthreads();
    for (int off = 1; off < 1024; off <<= 1) {
        int add = (t >= off) ? s[t - off] : 0;
        __syncthreads();
        s[t] += add;
        __syncthreads();
    }
    if (t < nb) bsum[t] = s[t] - v;
}

__global__ void finalize_k(int* __restrict__ rs, const int* __restrict__ bsum,
                           int* __restrict__ cursor) {
    int i = blockIdx.x * 256 + threadIdx.x;
    if (i < NNODES) {
        int v = rs[i] + bsum[blockIdx.x];
        rs[i] = v;
        cursor[i] = v;
    }
    if (i == 0) rs[NNODES] = NNZ_E;
}

__global__ void fill_k(const int* __restrict__ rows, const int* __restrict__ cols,
                       const float* __restrict__ vals, int* __restrict__ cursor,
                       int* __restrict__ ccol, float* __restrict__ cval) {
    int i = blockIdx.x * 256 + threadIdx.x;
    if (i < NNZ_E) {
        int r = rows[i];
        int p = atomicAdd(&cursor[r], 1);
        ccol[p] = cols[i];
        cval[p] = vals[i];
    }
}

// ---- dense init: h0 = esum = concat(user_emb, item_emb) -----------------

__global__ void init_k(const float4* __restrict__ ue, const float4* __restrict__ ie,
                       float4* __restrict__ h0, float4* __restrict__ esum) {
    int i = blockIdx.x * 256 + threadIdx.x;
    const int NU4 = NUSERS * (DIM / 4);   // 1,600,000
    const int NT4 = NNODES * (DIM / 4);   // 2,400,000
    if (i < NT4) {
        float4 v = (i < NU4) ? ue[i] : ie[i - NU4];
        h0[i]   = v;
        esum[i] = v;
    }
}

// ---- SpMM: one wave per row, lane = embedding dim -----------------------
// acc[lane] = sum_j cval[j] * x[ccol[j]*64 + lane]; esum += acc (fused);
// FINAL layer also applies *0.25 into esum (= d_out).

template <int FINAL>
__global__ void spmm_k(const int* __restrict__ rs, const int* __restrict__ ccol,
                       const float* __restrict__ cval, const float* __restrict__ x,
                       float* __restrict__ hout, float* __restrict__ esum) {
    int w    = (blockIdx.x * blockDim.x + threadIdx.x) >> 6;  // row id
    int lane = threadIdx.x & 63;                              // dim id
    if (w >= NNODES) return;
    int s = rs[w], e = rs[w + 1];
    float acc = 0.f;
    int j = s;
    // 4-wide unroll: 4 independent coalesced 256B gathers in flight
    for (; j + 4 <= e; j += 4) {
        int   c0 = ccol[j],     c1 = ccol[j + 1], c2 = ccol[j + 2], c3 = ccol[j + 3];
        float v0 = cval[j],     v1 = cval[j + 1], v2 = cval[j + 2], v3 = cval[j + 3];
        float x0 = x[c0 * DIM + lane];
        float x1 = x[c1 * DIM + lane];
        float x2 = x[c2 * DIM + lane];
        float x3 = x[c3 * DIM + lane];
        acc = fmaf(v0, x0, acc);
        acc = fmaf(v1, x1, acc);
        acc = fmaf(v2, x2, acc);
        acc = fmaf(v3, x3, acc);
    }
    for (; j < e; ++j) acc = fmaf(cval[j], x[ccol[j] * DIM + lane], acc);

    int o = w * DIM + lane;
    float r = esum[o] + acc;
    if (FINAL) {
        esum[o] = r * 0.25f;   // esum IS d_out
    } else {
        esum[o] = r;
        hout[o] = acc;
    }
}

// ---- launch -------------------------------------------------------------

extern "C" void kernel_launch(void* const* d_in, const int* in_sizes, int n_in,
                              void* d_out, int out_size, void* d_ws, size_t ws_size,
                              hipStream_t stream) {
    const float* ue   = (const float*)d_in[0];
    const float* ie   = (const float*)d_in[1];
    const float* vals = (const float*)d_in[2];
    const int*   rows = (const int*)d_in[3];
    const int*   cols = (const int*)d_in[4];
    float*       out  = (float*)d_out;   // doubles as emb_sum accumulator

    char*  ws  = (char*)d_ws;
    size_t off = 0;
    auto alloc = [&](size_t bytes) -> char* {
        char* p = ws + off;
        off += (bytes + 255) & ~size_t(255);
        return p;
    };
    float* h0     = (float*)alloc((size_t)NNODES * DIM * 4);  // 38.4 MB
    float* h1     = (float*)alloc((size_t)NNODES * DIM * 4);  // 38.4 MB
    float* cval   = (float*)alloc((size_t)NNZ_E * 4);         // 16 MB
    int*   ccol   = (int*)alloc((size_t)NNZ_E * 4);           // 16 MB
    int*   deg    = (int*)alloc((size_t)NNODES * 4);
    int*   rs     = (int*)alloc((size_t)(NNODES + 1) * 4);
    int*   cursor = (int*)alloc((size_t)NNODES * 4);
    int*   bsum   = (int*)alloc(1024 * 4);
    (void)in_sizes; (void)n_in; (void)out_size;

    // Workspace guard: if the harness gave us less than we need, do nothing.
    // d_out stays at the harness's memset(0) -> clean absmax-failure signature
    // (≈0.1367, same as the round-0 stub) instead of an OOB GPU fault.
    if (ws_size < off) return;

    // CSR build (amortized over the 3 SpMM layers)
    hipMemsetAsync(deg, 0, (size_t)NNODES * 4, stream);
    hist_k<<<(NNZ_E + 255) / 256, 256, 0, stream>>>(rows, deg);
    const int NB = (NNODES + 255) / 256;  // 586
    scan_block_k<<<NB, 256, 0, stream>>>(deg, rs, bsum);
    scan_bsum_k<<<1, 1024, 0, stream>>>(bsum, NB);
    finalize_k<<<NB, 256, 0, stream>>>(rs, bsum, cursor);
    fill_k<<<(NNZ_E + 255) / 256, 256, 0, stream>>>(rows, cols, vals, cursor, ccol, cval);

    // dense init: h0 = out(emb_sum) = all_emb
    init_k<<<(NNODES * (DIM / 4) + 255) / 256, 256, 0, stream>>>(
        (const float4*)ue, (const float4*)ie, (float4*)h0, (float4*)out);

    // 3 propagation layers, emb_sum fused; last layer fuses /4
    const int SG = (NNODES * 64) / 256;  // 37500 blocks, 4 waves (rows) each
    spmm_k<0><<<SG, 256, 0, stream>>>(rs, ccol, cval, h0, h1, out);
    spmm_k<0><<<SG, 256, 0, stream>>>(rs, ccol, cval, h1, h0, out);
    spmm_k<1><<<SG, 256, 0, stream>>>(rs, ccol, cval, h0, h1, out);
}

// Round 9
// 958.703 us; speedup vs baseline: 1.0773x; 1.0773x over previous
//
#include <hip/hip_runtime.h>
#include <hip/hip_bf16.h>

// LightGCN on MI355X: 3x SpMM (COO -> CSR built in-launch) + running sum.
// N_NODES=150000, DIM=64, NNZ=4M.
// R5 profile: fill_k top (281us, 370MB HBM write churn from 8M random 4B
// stores); spmm ~225us each at ~4.5TB/s effective gather (bytes-bound).
// R7: (a) fill_k packs (col,val) -> ONE int2 8B store/edge;
//     (b) h-state stored as bf16 -> gather bytes per edge 256B -> 128B.
//     esum stays fp32 (accumulated in fp32; bf16 error enters only via
//     stored h scaled by vals~0.01 -> added absmax ~1e-4, threshold 2.7e-3).

#define NUSERS 100000
#define NITEMS 50000
#define NNODES 150000
#define DIM    64
#define NNZ_E  4000000

__device__ inline unsigned short f2b(float f) {
    __hip_bfloat16 h = __float2bfloat16(f);   // RN
    return *reinterpret_cast<unsigned short*>(&h);
}
__device__ inline float b2f(unsigned short b) {
    return __uint_as_float((unsigned)b << 16);
}

// ---- CSR build ----------------------------------------------------------

__global__ void hist_k(const int* __restrict__ rows, int* __restrict__ deg) {
    int i = blockIdx.x * 256 + threadIdx.x;
    if (i < NNZ_E) atomicAdd(&deg[rows[i]], 1);
}

__global__ void scan_block_k(const int* __restrict__ deg, int* __restrict__ rs,
                             int* __restrict__ bsum) {
    __shared__ int s[256];
    int t = threadIdx.x;
    int i = blockIdx.x * 256 + t;
    int v = (i < NNODES) ? deg[i] : 0;
    s[t] = v;
    __syncthreads();
    for (int off = 1; off < 256; off <<= 1) {
        int add = (t >= off) ? s[t - off] : 0;
        __syncthreads();
        s[t] += add;
        __syncthreads();
    }
    if (i < NNODES) rs[i] = s[t] - v;          // exclusive within block
    if (t == 255) bsum[blockIdx.x] = s[255];   // block total
}

__global__ void scan_bsum_k(int* __restrict__ bsum, int nb) {
    __shared__ int s[1024];
    int t = threadIdx.x;
    int v = (t < nb) ? bsum[t] : 0;
    s[t] = v;
    __syncthreads();
    for (int off = 1; off < 1024; off <<= 1) {
        int add = (t >= off) ? s[t - off] : 0;
        __syncthreads();
        s[t] += add;
        __syncthreads();
    }
    if (t < nb) bsum[t] = s[t] - v;
}

__global__ void finalize_k(int* __restrict__ rs, const int* __restrict__ bsum,
                           int* __restrict__ cursor) {
    int i = blockIdx.x * 256 + threadIdx.x;
    if (i < NNODES) {
        int v = rs[i] + bsum[blockIdx.x];
        rs[i] = v;
        cursor[i] = v;
    }
    if (i == 0) rs[NNODES] = NNZ_E;
}

// ONE int2 8B scatter-store per edge (was 2x4B to two arrays)
__global__ void fill_k(const int* __restrict__ rows, const int* __restrict__ cols,
                       const float* __restrict__ vals, int* __restrict__ cursor,
                       int2* __restrict__ cedge) {
    int i = blockIdx.x * 256 + threadIdx.x;
    if (i < NNZ_E) {
        int r = rows[i];
        int p = atomicAdd(&cursor[r], 1);
        cedge[p] = make_int2(cols[i], __float_as_int(vals[i]));
    }
}

// ---- dense init: h0(bf16) = all_emb; esum(fp32, = d_out) = all_emb ------

__global__ void init_k(const float4* __restrict__ ue, const float4* __restrict__ ie,
                       ushort4* __restrict__ h0, float4* __restrict__ esum) {
    int i = blockIdx.x * 256 + threadIdx.x;
    const int NU4 = NUSERS * (DIM / 4);   // 1,600,000
    const int NT4 = NNODES * (DIM / 4);   // 2,400,000
    if (i < NT4) {
        float4 v = (i < NU4) ? ue[i] : ie[i - NU4];
        esum[i] = v;
        ushort4 b;
        b.x = f2b(v.x); b.y = f2b(v.y); b.z = f2b(v.z); b.w = f2b(v.w);
        h0[i] = b;
    }
}

// ---- SpMM: one wave per row, lane = dim; x/hout bf16, esum fp32 ---------

template <int FINAL>
__global__ void spmm_k(const int* __restrict__ rs, const int2* __restrict__ cedge,
                       const unsigned short* __restrict__ x,
                       unsigned short* __restrict__ hout, float* __restrict__ esum) {
    int w    = (blockIdx.x * blockDim.x + threadIdx.x) >> 6;  // row id
    int lane = threadIdx.x & 63;                              // dim id
    if (w >= NNODES) return;
    int s = rs[w], e = rs[w + 1];
    float acc = 0.f;
    int j = s;
    // 4-wide unroll: 4 independent coalesced 128B gathers in flight
    for (; j + 4 <= e; j += 4) {
        int2 e0 = cedge[j],     e1 = cedge[j + 1];
        int2 e2 = cedge[j + 2], e3 = cedge[j + 3];
        float x0 = b2f(x[e0.x * DIM + lane]);
        float x1 = b2f(x[e1.x * DIM + lane]);
        float x2 = b2f(x[e2.x * DIM + lane]);
        float x3 = b2f(x[e3.x * DIM + lane]);
        acc = fmaf(__int_as_float(e0.y), x0, acc);
        acc = fmaf(__int_as_float(e1.y), x1, acc);
        acc = fmaf(__int_as_float(e2.y), x2, acc);
        acc = fmaf(__int_as_float(e3.y), x3, acc);
    }
    for (; j < e; ++j) {
        int2 ee = cedge[j];
        acc = fmaf(__int_as_float(ee.y), b2f(x[ee.x * DIM + lane]), acc);
    }

    int o = w * DIM + lane;
    float r = esum[o] + acc;
    if (FINAL) {
        esum[o] = r * 0.25f;   // esum IS d_out
    } else {
        esum[o] = r;
        hout[o] = f2b(acc);
    }
}

// ---- launch -------------------------------------------------------------

extern "C" void kernel_launch(void* const* d_in, const int* in_sizes, int n_in,
                              void* d_out, int out_size, void* d_ws, size_t ws_size,
                              hipStream_t stream) {
    const float* ue   = (const float*)d_in[0];
    const float* ie   = (const float*)d_in[1];
    const float* vals = (const float*)d_in[2];
    const int*   rows = (const int*)d_in[3];
    const int*   cols = (const int*)d_in[4];
    float*       out  = (float*)d_out;   // doubles as emb_sum accumulator

    char*  ws  = (char*)d_ws;
    size_t off = 0;
    auto alloc = [&](size_t bytes) -> char* {
        char* p = ws + off;
        off += (bytes + 255) & ~size_t(255);
        return p;
    };
    unsigned short* h0 = (unsigned short*)alloc((size_t)NNODES * DIM * 2);  // 19.2 MB
    unsigned short* h1 = (unsigned short*)alloc((size_t)NNODES * DIM * 2);  // 19.2 MB
    int2*  cedge  = (int2*)alloc((size_t)NNZ_E * 8);                        // 32 MB
    int*   deg    = (int*)alloc((size_t)NNODES * 4);
    int*   rs     = (int*)alloc((size_t)(NNODES + 1) * 4);
    int*   cursor = (int*)alloc((size_t)NNODES * 4);
    int*   bsum   = (int*)alloc(1024 * 4);
    (void)in_sizes; (void)n_in; (void)out_size;

    // Workspace guard: insufficient ws -> launch nothing (clean absmax fail,
    // not an OOB fault).
    if (ws_size < off) return;

    // CSR build (amortized over the 3 SpMM layers)
    hipMemsetAsync(deg, 0, (size_t)NNODES * 4, stream);
    hist_k<<<(NNZ_E + 255) / 256, 256, 0, stream>>>(rows, deg);
    const int NB = (NNODES + 255) / 256;  // 586
    scan_block_k<<<NB, 256, 0, stream>>>(deg, rs, bsum);
    scan_bsum_k<<<1, 1024, 0, stream>>>(bsum, NB);
    finalize_k<<<NB, 256, 0, stream>>>(rs, bsum, cursor);
    fill_k<<<(NNZ_E + 255) / 256, 256, 0, stream>>>(rows, cols, vals, cursor, cedge);

    // dense init: h0(bf16) = all_emb, out(fp32 esum) = all_emb
    init_k<<<(NNODES * (DIM / 4) + 255) / 256, 256, 0, stream>>>(
        (const float4*)ue, (const float4*)ie, (ushort4*)h0, (float4*)out);

    // 3 propagation layers, emb_sum fused; last layer fuses /4
    const int SG = (NNODES * 64) / 256;  // 37500 blocks, 4 waves (rows) each
    spmm_k<0><<<SG, 256, 0, stream>>>(rs, cedge, h0, h1, out);
    spmm_k<0><<<SG, 256, 0, stream>>>(rs, cedge, h1, h0, out);
    spmm_k<1><<<SG, 256, 0, stream>>>(rs, cedge, h0, h1, out);
}